// Round 17
// baseline (119.878 us; speedup 1.0000x reference)
//
#include <hip/hip_runtime.h>
#include <stdint.h>

#define B_ 2
#define T_ 2048
#define D_ 1024
#define H_ 16
#define DH_ 64
#define N3_ 3072
#define M_ 4096

typedef __attribute__((ext_vector_type(8))) short short8;
typedef __attribute__((ext_vector_type(4))) float f32x4;

typedef const uint32_t __attribute__((address_space(1))) gu32;
typedef uint32_t __attribute__((address_space(3))) lu32;

__device__ __forceinline__ void gload_lds16(const void* g, void* l) {
  __builtin_amdgcn_global_load_lds((gu32*)g, (lu32*)l, 16, 0, 0);
}

__device__ __forceinline__ uint16_t f2bf(float f) {
  union { float f; uint32_t u; } c; c.f = f;
  uint32_t u = c.u;
  return (uint16_t)((u + 0x7fffu + ((u >> 16) & 1u)) >> 16);
}

__device__ __forceinline__ uint32_t cvtpk_bf16(float lo, float hi) {
  uint32_t r;
  asm("v_cvt_pk_bf16_f32 %0, %1, %2" : "=v"(r) : "v"(lo), "v"(hi));
  return r;
}

// ---------------- fused pre-pass: convert x + transpose both W ----------------
// blocks [0,1024): x f32->bf16 ; [1024,4096): Wqkv^T ; [4096,5120): Wo^T
__global__ __launch_bounds__(256)
void k_prep(const float* __restrict__ x, const float* __restrict__ Wqkv,
            const float* __restrict__ Wo, uint16_t* __restrict__ xb,
            uint16_t* __restrict__ wqkvt, uint16_t* __restrict__ wot) {
  const int bid = blockIdx.x, tid = threadIdx.x;
  if (bid < 1024) {
#pragma unroll
    for (int it = 0; it < 4; it++) {
      const int i = (bid * 256 + tid) * 4 + it * 1048576;
      float4 v = *reinterpret_cast<const float4*>(x + i);
      ushort4 ov;
      ov.x = f2bf(v.x); ov.y = f2bf(v.y); ov.z = f2bf(v.z); ov.w = f2bf(v.w);
      *reinterpret_cast<ushort4*>(xb + i) = ov;
    }
    return;
  }
  __shared__ float tile[32][33];
  const float* W; uint16_t* Wt; int K, N, nb, kb;
  if (bid < 4096) {
    const int idx = bid - 1024;
    W = Wqkv; Wt = wqkvt; K = D_; N = N3_;
    nb = (idx % 96) * 32; kb = (idx / 96) * 32;
  } else {
    const int idx = bid - 4096;
    W = Wo; Wt = wot; K = D_; N = D_;
    nb = (idx & 31) * 32; kb = (idx >> 5) * 32;
  }
  const int tx = tid & 31, ty = tid >> 5;
#pragma unroll
  for (int i = 0; i < 4; i++)
    tile[ty + i * 8][tx] = W[(size_t)(kb + ty + i * 8) * N + nb + tx];
  __syncthreads();
#pragma unroll
  for (int i = 0; i < 4; i++) {
    const int nl = ty + i * 8;
    Wt[(size_t)(nb + nl) * K + kb + tx] = f2bf(tile[tx][nl]);
  }
}

// ---------------- GEMM1: 128x64 tile -> grid 1536 = occupancy 4 blocks/CU ----------------
// qkv[4096][3072] bf16 = xb * wqkvt^T + bias, QS on Q cols, VT on V cols.
// R16-proven k_gemm2 geometry (was grid-limited at 3 blocks/CU with 128²).
__global__ __launch_bounds__(256)
void k_gemm1(const uint16_t* __restrict__ A, const uint16_t* __restrict__ Bt,
             const float* __restrict__ bias, uint16_t* __restrict__ Cv,
             uint16_t* __restrict__ vtO) {
  constexpr int BK = 32;
  __shared__ uint16_t As[128 * BK];  // 8 KB
  __shared__ uint16_t Bs[64 * BK];   // 4 KB
  const int tid = threadIdx.x;
  const int w = tid >> 6, lane = tid & 63;
  const int l16 = lane & 15, lg = lane >> 4;
  const int bm = blockIdx.x * 128, bn = blockIdx.y * 64;
  const int wr = (w >> 1) * 64, wc = (w & 1) * 32;
  f32x4 acc[4][2] = {};
  for (int kt = 0; kt < D_; kt += BK) {
    __syncthreads();
    {
#pragma unroll
      for (int j = 0; j < 2; j++) {             // As: 512 x 16B chunks
        const int c = j * 256 + tid;
        const int row = c >> 2, cole = (c & 3) * 8;
        gload_lds16(A + (size_t)(bm + row) * D_ + kt + cole, (char*)As + c * 16);
      }
      const int c = tid;                        // Bs: 256 x 16B chunks
      const int row = c >> 2, cole = (c & 3) * 8;
      gload_lds16(Bt + (size_t)(bn + row) * D_ + kt + cole, (char*)Bs + c * 16);
    }
    __syncthreads();
    short8 aF[4], bF[2];
#pragma unroll
    for (int f = 0; f < 4; f++)
      aF[f] = *(const short8*)(As + (wr + f * 16 + l16) * BK + lg * 8);
#pragma unroll
    for (int f = 0; f < 2; f++)
      bF[f] = *(const short8*)(Bs + (wc + f * 16 + l16) * BK + lg * 8);
#pragma unroll
    for (int mf = 0; mf < 4; mf++)
#pragma unroll
      for (int nf = 0; nf < 2; nf++)
        acc[mf][nf] = __builtin_amdgcn_mfma_f32_16x16x32_bf16(aF[mf], bF[nf], acc[mf][nf], 0, 0, 0);
  }
#pragma unroll
  for (int nf = 0; nf < 2; nf++) {
    const int col = bn + wc + nf * 16 + l16;
    const float bv = bias[col];
    const float sc = (col < H_ * DH_) ? 0.18033688f : 1.0f;  // 0.125*log2e
    const bool vcol = (col >= 2 * H_ * DH_);
#pragma unroll
    for (int mf = 0; mf < 4; mf++) {
      const int row0 = bm + wr + mf * 16 + lg * 4;
      if (vcol) {
        // transposed V store: Vt[bh][d][t0..t0+3]
        const int cv = col - 2 * H_ * DH_;
        const int hh = cv >> 6, dd = cv & 63;
        const int bb = row0 >> 11, t0 = row0 & 2047;
        uint64_t p4 = 0;
#pragma unroll
        for (int r = 0; r < 4; r++)
          p4 |= (uint64_t)f2bf(acc[mf][nf][r] + bv) << (16 * r);
        *(uint64_t*)(vtO + ((size_t)(bb * 16 + hh) * DH_ + dd) * T_ + t0) = p4;
      } else {
#pragma unroll
        for (int r = 0; r < 4; r++)
          Cv[(size_t)(row0 + r) * N3_ + col] = f2bf((acc[mf][nf][r] + bv) * sc);
      }
    }
  }
}

// ---------------- GEMM2: 128x64 tile (R16-proven), f32 out + bias ----------------
__global__ __launch_bounds__(256)
void k_gemm2(const uint16_t* __restrict__ A, const uint16_t* __restrict__ Bt,
             const float* __restrict__ bias, float* __restrict__ C) {
  constexpr int BK = 32;
  __shared__ uint16_t As[128 * BK];  // 8 KB
  __shared__ uint16_t Bs[64 * BK];   // 4 KB
  const int tid = threadIdx.x;
  const int w = tid >> 6, lane = tid & 63;
  const int l16 = lane & 15, lg = lane >> 4;
  const int bm = blockIdx.x * 128, bn = blockIdx.y * 64;
  const int wr = (w >> 1) * 64, wc = (w & 1) * 32;
  f32x4 acc[4][2] = {};
  for (int kt = 0; kt < D_; kt += BK) {
    __syncthreads();
    {
#pragma unroll
      for (int j = 0; j < 2; j++) {             // As: 512 x 16B chunks
        const int c = j * 256 + tid;
        const int row = c >> 2, cole = (c & 3) * 8;
        gload_lds16(A + (size_t)(bm + row) * D_ + kt + cole, (char*)As + c * 16);
      }
      const int c = tid;                        // Bs: 256 x 16B chunks
      const int row = c >> 2, cole = (c & 3) * 8;
      gload_lds16(Bt + (size_t)(bn + row) * D_ + kt + cole, (char*)Bs + c * 16);
    }
    __syncthreads();
    short8 aF[4], bF[2];
#pragma unroll
    for (int f = 0; f < 4; f++)
      aF[f] = *(const short8*)(As + (wr + f * 16 + l16) * BK + lg * 8);
#pragma unroll
    for (int f = 0; f < 2; f++)
      bF[f] = *(const short8*)(Bs + (wc + f * 16 + l16) * BK + lg * 8);
#pragma unroll
    for (int mf = 0; mf < 4; mf++)
#pragma unroll
      for (int nf = 0; nf < 2; nf++)
        acc[mf][nf] = __builtin_amdgcn_mfma_f32_16x16x32_bf16(aF[mf], bF[nf], acc[mf][nf], 0, 0, 0);
  }
#pragma unroll
  for (int nf = 0; nf < 2; nf++) {
    const int col = bn + wc + nf * 16 + l16;
    const float bv = bias[col];
#pragma unroll
    for (int mf = 0; mf < 4; mf++) {
      const int row0 = bm + wr + mf * 16 + lg * 4;
#pragma unroll
      for (int r = 0; r < 4; r++)
        C[(size_t)(row0 + r) * D_ + col] = acc[mf][nf][r] + bv;
    }
  }
}

// ---------------- flash attention v7 (R15-proven): key-split load balance ----------------
__global__ __launch_bounds__(512, 4)
void k_attn7(const uint16_t* __restrict__ qkv, const uint16_t* __restrict__ vt,
             const float* __restrict__ sink, uint16_t* __restrict__ z) {
  __shared__ uint16_t Ks[2][2][64 * 64];   // [buf][half][key][d]; scratch after loop
  __shared__ uint16_t Vs[2][2][64 * 64];   // [buf][half][d][key]
  __shared__ uint16_t Ps[8][16 * 64];
  const int bid = blockIdx.x;
  const int bh = (bid & 7) * 4 + (bid >> 7);  // 4 consecutive heads per XCD
  const int jp = (bid >> 3) & 15;
  const int b = bh >> 4, h = bh & 15;
  const int tid = threadIdx.x, w = tid >> 6;
  const int lane = tid & 63, l16 = lane & 15, lg = lane >> 4;
  const bool gA = (w < 4);
  const int wq = w & 3;
  const int q31 = 31 - jp;
  const int NIT = (33 - jp) >> 1;
  const int qbJ = jp * 64 + wq * 16;
  const int qb3 = q31 * 64 + wq * 16;
  const uint16_t* Qg = qkv + (size_t)b * T_ * N3_ + h * DH_;
  const uint16_t* Kg = Qg + H_ * DH_;
  const uint16_t* Vtg = vt + (size_t)bh * DH_ * T_;
  short8 qFj[2], qF3[2];
#pragma unroll
  for (int kf = 0; kf < 2; kf++) {
    qF3[kf] = *(const short8*)(Qg + (size_t)(qb3 + l16) * N3_ + kf * 32 + lg * 8);
    if (gA)
      qFj[kf] = *(const short8*)(Qg + (size_t)(qbJ + l16) * N3_ + kf * 32 + lg * 8);
  }
  const float sk2 = sink[h] * 1.44269504f;
  float mJ = sk2, lJ = (lg == 0) ? 1.f : 0.f;   // A: jp-block state (sink)
  float m3 = gA ? -1e38f : sk2;                 // 31-block: A partial / B (sink)
  float l3 = (!gA && lg == 0) ? 1.f : 0.f;
  f32x4 oJ[4] = {}, o3[4] = {};

  auto STAGE = [&](int buf, int half, int kt) {
    const int row = tid >> 3, c = tid & 7;
    const int cg = c ^ (row & 7);  // pre-swizzled global source (m173)
    gload_lds16(Kg + (size_t)(kt * 64 + row) * N3_ + cg * 8,
                (char*)&Ks[buf][half][0] + w * 1024 + lane * 16);
    gload_lds16(Vtg + (size_t)row * T_ + kt * 64 + cg * 8,
                (char*)&Vs[buf][half][0] + w * 1024 + lane * 16);
  };

  int cur = 0;
  auto computeSub = [&](int sub, int qblkP, int qbR, const short8* qFp,
                        float& mR, float& lR, f32x4* oR) {
    const int half = sub & 1;
    short8 kF[2][4];
#pragma unroll
    for (int kf = 0; kf < 2; kf++)
#pragma unroll
      for (int nf = 0; nf < 4; nf++) {
        const int row = nf * 16 + l16;
        const int cc = (kf * 4 + lg) ^ (l16 & 7);
        kF[kf][nf] = *(const short8*)(&Ks[cur][half][0] + row * 64 + cc * 8);
      }
    f32x4 s[4];
    __builtin_amdgcn_s_setprio(1);
#pragma unroll
    for (int nf = 0; nf < 4; nf++) {
      f32x4 t = {};
      t = __builtin_amdgcn_mfma_f32_16x16x32_bf16(kF[0][nf], qFp[0], t, 0, 0, 0);
      t = __builtin_amdgcn_mfma_f32_16x16x32_bf16(kF[1][nf], qFp[1], t, 0, 0, 0);
      s[nf] = t;
    }
    __builtin_amdgcn_s_setprio(0);
    const bool diag = (sub == qblkP);
    float mt = -3e38f;
    if (diag) {
#pragma unroll
      for (int nf = 0; nf < 4; nf++)
#pragma unroll
        for (int r = 0; r < 4; r++) {
          float v = s[nf][r];
          if (sub * 64 + nf * 16 + lg * 4 + r > qbR + l16) v = -3e38f;
          s[nf][r] = v;
          mt = fmaxf(mt, v);
        }
    } else {
#pragma unroll
      for (int nf = 0; nf < 4; nf++)
#pragma unroll
        for (int r = 0; r < 4; r++) mt = fmaxf(mt, s[nf][r]);
    }
    mt = fmaxf(mt, __shfl_xor(mt, 16));
    mt = fmaxf(mt, __shfl_xor(mt, 32));
    if (!__all(mt <= mR + 8.0f)) {   // T13 defer-rescale
      const float mnew = fmaxf(mR, mt);
      const float alpha = exp2f(mR - mnew);
      mR = mnew;
      lR *= alpha;
      float ar[4];
#pragma unroll
      for (int r = 0; r < 4; r++) ar[r] = __shfl(alpha, lg * 4 + r);
#pragma unroll
      for (int df = 0; df < 4; df++)
#pragma unroll
        for (int r = 0; r < 4; r++) oR[df][r] *= ar[r];
    }
    float ps = 0.f;
#pragma unroll
    for (int nf = 0; nf < 4; nf++)
#pragma unroll
      for (int r = 0; r < 4; r++) {
        const float p = exp2f(s[nf][r] - mR);
        s[nf][r] = p;
        ps += p;
      }
    lR += ps;
#pragma unroll
    for (int nf = 0; nf < 4; nf++) {
      uint2 pw;
      pw.x = cvtpk_bf16(s[nf][0], s[nf][1]);
      pw.y = cvtpk_bf16(s[nf][2], s[nf][3]);
      const int cc = (nf * 2 + (lg >> 1)) ^ (l16 & 7);
      *(uint2*)((char*)&Ps[w][0] + l16 * 128 + cc * 16 + (lg & 1) * 8) = pw;
    }
    __builtin_amdgcn_s_setprio(1);
#pragma unroll
    for (int ks = 0; ks < 2; ks++) {
      const int cp = (ks * 4 + lg) ^ (l16 & 7);
      const short8 pF = *(const short8*)((char*)&Ps[w][0] + l16 * 128 + cp * 16);
#pragma unroll
      for (int df = 0; df < 4; df++) {
        const short8 vF = *(const short8*)((char*)&Vs[cur][half][0] + (df * 16 + l16) * 128 + cp * 16);
        oR[df] = __builtin_amdgcn_mfma_f32_16x16x32_bf16(pF, vF, oR[df], 0, 0, 0);
      }
    }
    __builtin_amdgcn_s_setprio(0);
  };

  STAGE(0, 0, 0);
  STAGE(0, 1, 1);
  __syncthreads();
  for (int kt2 = 0; kt2 < NIT; kt2++) {
    if (kt2 + 1 < NIT) {
      STAGE(cur ^ 1, 0, 2 * kt2 + 2);
      STAGE(cur ^ 1, 1, 2 * kt2 + 3);
    }
    const int s0 = 2 * kt2, s1 = s0 + 1;
    if (gA) {                       // wave-uniform branches
      if (s0 <= jp) computeSub(s0, jp, qbJ, qFj, mJ, lJ, oJ);
      if (s1 <= jp) computeSub(s1, jp, qbJ, qFj, mJ, lJ, oJ);
      if (s0 > jp)  computeSub(s0, q31, qb3, qF3, m3, l3, o3);  // even steal
    } else {
      if (s0 <= jp)  computeSub(s0, q31, qb3, qF3, m3, l3, o3);
      if (s1 <= q31) computeSub(s1, q31, qb3, qF3, m3, l3, o3); // all odds
    }
    __syncthreads();
    cur ^= 1;
  }

  // ---- epilogue: A publishes 31-partial + stores jp rows; B merges + stores ----
  if (gA) {
    l3 += __shfl_xor(l3, 16);
    l3 += __shfl_xor(l3, 32);
    float* sc = (float*)&Ks[0][0][0] + w * 1152;  // 64 lanes x 17 f32 (padded)
#pragma unroll
    for (int df = 0; df < 4; df++)
#pragma unroll
      for (int r = 0; r < 4; r++) sc[lane * 17 + df * 4 + r] = o3[df][r];
    float* ml = (float*)&Ps[w][0];
    if (lg == 0) { ml[l16] = m3; ml[16 + l16] = l3; }
  }
  __syncthreads();
  if (gA) {
    lJ += __shfl_xor(lJ, 16);
    lJ += __shfl_xor(lJ, 32);
#pragma unroll
    for (int r = 0; r < 4; r++) {
      const float inv = 1.f / __shfl(lJ, lg * 4 + r);
      const int qa = qbJ + lg * 4 + r;
      uint16_t* zp = z + (size_t)(b * T_ + qa) * (H_ * DH_) + h * DH_;
#pragma unroll
      for (int df = 0; df < 4; df++) zp[df * 16 + l16] = f2bf(oJ[df][r] * inv);
    }
  } else {
    const float* sc = (const float*)&Ks[0][0][0] + (w - 4) * 1152;
    const float* ml = (const float*)&Ps[w - 4][0];
    const float mA = ml[l16], lA = ml[16 + l16];
    l3 += __shfl_xor(l3, 16);
    l3 += __shfl_xor(l3, 32);
    const float mF = fmaxf(m3, mA);
    const float aB = exp2f(m3 - mF), aA = exp2f(mA - mF);
    const float lF = l3 * aB + lA * aA;
#pragma unroll
    for (int r = 0; r < 4; r++) {
      const float aBr = __shfl(aB, lg * 4 + r);
      const float aAr = __shfl(aA, lg * 4 + r);
      const float inv = 1.f / __shfl(lF, lg * 4 + r);
      const int qa = qb3 + lg * 4 + r;
      uint16_t* zp = z + (size_t)(b * T_ + qa) * (H_ * DH_) + h * DH_;
#pragma unroll
      for (int df = 0; df < 4; df++) {
        const float oA = sc[lane * 17 + df * 4 + r];
        zp[df * 16 + l16] = f2bf((o3[df][r] * aBr + oA * aAr) * inv);
      }
    }
  }
}

extern "C" void kernel_launch(void* const* d_in, const int* in_sizes, int n_in,
                              void* d_out, int out_size, void* d_ws, size_t ws_size,
                              hipStream_t stream) {
  const float* x    = (const float*)d_in[0];
  const float* Wqkv = (const float*)d_in[1];
  const float* bqkv = (const float*)d_in[2];
  const float* Wo   = (const float*)d_in[3];
  const float* bo   = (const float*)d_in[4];
  const float* sink = (const float*)d_in[5];

  // workspace layout (48 MB total):
  //  0- 8 MB : xb (x bf16; dead after gemm1)  /  zb (attn out; aliases xb)
  //  8-14 MB : W_QKV^T bf16
  // 14-16 MB : W_O^T bf16
  // 16-24 MB : Vt[bh][d][t] bf16 (written by gemm1 epilogue)
  // 24-48 MB : qkv bf16 (Q,K used; V region unwritten)
  char* ws = (char*)d_ws;
  uint16_t* xb    = (uint16_t*)(ws);
  uint16_t* zb    = (uint16_t*)(ws);
  uint16_t* wqkvt = (uint16_t*)(ws + (size_t)8  * 1048576);
  uint16_t* wot   = (uint16_t*)(ws + (size_t)14 * 1048576);
  uint16_t* vtb   = (uint16_t*)(ws + (size_t)16 * 1048576);
  uint16_t* qkvb  = (uint16_t*)(ws + (size_t)24 * 1048576);

  k_prep<<<5120, 256, 0, stream>>>(x, Wqkv, Wo, xb, wqkvt, wot);
  k_gemm1<<<dim3(M_ / 128, N3_ / 64), 256, 0, stream>>>(xb, wqkvt, bqkv, qkvb, vtb);
  k_attn7<<<dim3(512), 512, 0, stream>>>(qkvb, vtb, sink, zb);
  k_gemm2<<<dim3(M_ / 128, D_ / 64), 256, 0, stream>>>(zb, wot, bo, (float*)d_out);
}

// Round 18
// 115.637 us; speedup vs baseline: 1.0367x; 1.0367x over previous
//
#include <hip/hip_runtime.h>
#include <stdint.h>

#define B_ 2
#define T_ 2048
#define D_ 1024
#define H_ 16
#define DH_ 64
#define N3_ 3072
#define M_ 4096

typedef __attribute__((ext_vector_type(8))) short short8;
typedef __attribute__((ext_vector_type(4))) float f32x4;

typedef const uint32_t __attribute__((address_space(1))) gu32;
typedef uint32_t __attribute__((address_space(3))) lu32;

__device__ __forceinline__ void gload_lds16(const void* g, void* l) {
  __builtin_amdgcn_global_load_lds((gu32*)g, (lu32*)l, 16, 0, 0);
}

__device__ __forceinline__ uint16_t f2bf(float f) {
  union { float f; uint32_t u; } c; c.f = f;
  uint32_t u = c.u;
  return (uint16_t)((u + 0x7fffu + ((u >> 16) & 1u)) >> 16);
}

__device__ __forceinline__ uint32_t cvtpk_bf16(float lo, float hi) {
  uint32_t r;
  asm("v_cvt_pk_bf16_f32 %0, %1, %2" : "=v"(r) : "v"(lo), "v"(hi));
  return r;
}

// ---------------- fused pre-pass: convert x + transpose both W ----------------
// blocks [0,1024): x f32->bf16 ; [1024,4096): Wqkv^T ; [4096,5120): Wo^T
__global__ __launch_bounds__(256)
void k_prep(const float* __restrict__ x, const float* __restrict__ Wqkv,
            const float* __restrict__ Wo, uint16_t* __restrict__ xb,
            uint16_t* __restrict__ wqkvt, uint16_t* __restrict__ wot) {
  const int bid = blockIdx.x, tid = threadIdx.x;
  if (bid < 1024) {
#pragma unroll
    for (int it = 0; it < 4; it++) {
      const int i = (bid * 256 + tid) * 4 + it * 1048576;
      float4 v = *reinterpret_cast<const float4*>(x + i);
      ushort4 ov;
      ov.x = f2bf(v.x); ov.y = f2bf(v.y); ov.z = f2bf(v.z); ov.w = f2bf(v.w);
      *reinterpret_cast<ushort4*>(xb + i) = ov;
    }
    return;
  }
  __shared__ float tile[32][33];
  const float* W; uint16_t* Wt; int K, N, nb, kb;
  if (bid < 4096) {
    const int idx = bid - 1024;
    W = Wqkv; Wt = wqkvt; K = D_; N = N3_;
    nb = (idx % 96) * 32; kb = (idx / 96) * 32;
  } else {
    const int idx = bid - 4096;
    W = Wo; Wt = wot; K = D_; N = D_;
    nb = (idx & 31) * 32; kb = (idx >> 5) * 32;
  }
  const int tx = tid & 31, ty = tid >> 5;
#pragma unroll
  for (int i = 0; i < 4; i++)
    tile[ty + i * 8][tx] = W[(size_t)(kb + ty + i * 8) * N + nb + tx];
  __syncthreads();
#pragma unroll
  for (int i = 0; i < 4; i++) {
    const int nl = ty + i * 8;
    Wt[(size_t)(nb + nl) * K + kb + tx] = f2bf(tile[tx][nl]);
  }
}

// ---------------- GEMM1: 128² template (R16-proven) ----------------
// QS: pre-scale Q columns (col < 1024) by 0.125*log2(e).
// VT: V columns (col >= 2048) written TRANSPOSED to vtO[bh][d][t] (b64 packed).
template <bool OUT_BF16, bool QS, bool VT>
__global__ __launch_bounds__(256)
void k_gemm_bt(const uint16_t* __restrict__ A, const uint16_t* __restrict__ Bt,
               const float* __restrict__ bias, void* __restrict__ Cv,
               uint16_t* __restrict__ vtO, int M, int N, int K) {
  constexpr int BK = 32;
  __shared__ uint16_t As[128 * BK];
  __shared__ uint16_t Bs[128 * BK];
  const int tid = threadIdx.x;
  const int w = tid >> 6, lane = tid & 63;
  const int l16 = lane & 15, lg = lane >> 4;
  const int bm = blockIdx.x * 128, bn = blockIdx.y * 128;
  const int wr = (w >> 1) * 64, wc = (w & 1) * 64;
  f32x4 acc[4][4] = {};
  for (int kt = 0; kt < K; kt += BK) {
    __syncthreads();
#pragma unroll
    for (int j = 0; j < 2; j++) {
      const int slot = j * 4 + w;
      const int bbyte = slot * 1024 + lane * 16;
      const int row = bbyte >> 6;
      const int cole = (bbyte & 63) >> 1;
      gload_lds16(A + (size_t)(bm + row) * K + kt + cole, (char*)As + slot * 1024);
      gload_lds16(Bt + (size_t)(bn + row) * K + kt + cole, (char*)Bs + slot * 1024);
    }
    __syncthreads();
    short8 aF[4], bF[4];
#pragma unroll
    for (int f = 0; f < 4; f++) {
      aF[f] = *(const short8*)(As + (wr + f * 16 + l16) * BK + lg * 8);
      bF[f] = *(const short8*)(Bs + (wc + f * 16 + l16) * BK + lg * 8);
    }
#pragma unroll
    for (int mf = 0; mf < 4; mf++)
#pragma unroll
      for (int nf = 0; nf < 4; nf++)
        acc[mf][nf] = __builtin_amdgcn_mfma_f32_16x16x32_bf16(aF[mf], bF[nf], acc[mf][nf], 0, 0, 0);
  }
#pragma unroll
  for (int nf = 0; nf < 4; nf++) {
    const int col = bn + wc + nf * 16 + l16;
    const float bv = bias ? bias[col] : 0.0f;
    const float sc = (QS && col < H_ * DH_) ? 0.18033688f : 1.0f;  // 0.125*log2e
    const bool vcol = VT && (col >= 2 * H_ * DH_);
#pragma unroll
    for (int mf = 0; mf < 4; mf++) {
      const int row0 = bm + wr + mf * 16 + lg * 4;
      if (vcol) {
        const int cv = col - 2 * H_ * DH_;
        const int hh = cv >> 6, dd = cv & 63;
        const int bb = row0 >> 11, t0 = row0 & 2047;
        uint64_t p4 = 0;
#pragma unroll
        for (int r = 0; r < 4; r++)
          p4 |= (uint64_t)f2bf(acc[mf][nf][r] + bv) << (16 * r);
        *(uint64_t*)(vtO + ((size_t)(bb * 16 + hh) * DH_ + dd) * T_ + t0) = p4;
      } else {
#pragma unroll
        for (int r = 0; r < 4; r++) {
          const float v = (acc[mf][nf][r] + bv) * sc;
          if (OUT_BF16)
            ((uint16_t*)Cv)[(size_t)(row0 + r) * N + col] = f2bf(v);
          else
            ((float*)Cv)[(size_t)(row0 + r) * N + col] = v;
        }
      }
    }
  }
}

// ---------------- GEMM2: 128x64 tile (R16-proven) -> 2 blocks/CU ----------------
__global__ __launch_bounds__(256)
void k_gemm2(const uint16_t* __restrict__ A, const uint16_t* __restrict__ Bt,
             const float* __restrict__ bias, float* __restrict__ C) {
  constexpr int BK = 32;
  __shared__ uint16_t As[128 * BK];  // 8 KB
  __shared__ uint16_t Bs[64 * BK];   // 4 KB
  const int tid = threadIdx.x;
  const int w = tid >> 6, lane = tid & 63;
  const int l16 = lane & 15, lg = lane >> 4;
  const int bm = blockIdx.x * 128, bn = blockIdx.y * 64;
  const int wr = (w >> 1) * 64, wc = (w & 1) * 32;
  f32x4 acc[4][2] = {};
  for (int kt = 0; kt < D_; kt += BK) {
    __syncthreads();
    {
#pragma unroll
      for (int j = 0; j < 2; j++) {             // As: 512 x 16B chunks
        const int c = j * 256 + tid;
        const int row = c >> 2, cole = (c & 3) * 8;
        gload_lds16(A + (size_t)(bm + row) * D_ + kt + cole, (char*)As + c * 16);
      }
      const int c = tid;                        // Bs: 256 x 16B chunks
      const int row = c >> 2, cole = (c & 3) * 8;
      gload_lds16(Bt + (size_t)(bn + row) * D_ + kt + cole, (char*)Bs + c * 16);
    }
    __syncthreads();
    short8 aF[4], bF[2];
#pragma unroll
    for (int f = 0; f < 4; f++)
      aF[f] = *(const short8*)(As + (wr + f * 16 + l16) * BK + lg * 8);
#pragma unroll
    for (int f = 0; f < 2; f++)
      bF[f] = *(const short8*)(Bs + (wc + f * 16 + l16) * BK + lg * 8);
#pragma unroll
    for (int mf = 0; mf < 4; mf++)
#pragma unroll
      for (int nf = 0; nf < 2; nf++)
        acc[mf][nf] = __builtin_amdgcn_mfma_f32_16x16x32_bf16(aF[mf], bF[nf], acc[mf][nf], 0, 0, 0);
  }
#pragma unroll
  for (int nf = 0; nf < 2; nf++) {
    const int col = bn + wc + nf * 16 + l16;
    const float bv = bias[col];
#pragma unroll
    for (int mf = 0; mf < 4; mf++) {
      const int row0 = bm + wr + mf * 16 + lg * 4;
#pragma unroll
      for (int r = 0; r < 4; r++)
        C[(size_t)(row0 + r) * D_ + col] = acc[mf][nf][r] + bv;
    }
  }
}

// ---------------- flash attention v7 (R15-proven): key-split load balance ----------------
__global__ __launch_bounds__(512, 4)
void k_attn7(const uint16_t* __restrict__ qkv, const uint16_t* __restrict__ vt,
             const float* __restrict__ sink, uint16_t* __restrict__ z) {
  __shared__ uint16_t Ks[2][2][64 * 64];   // [buf][half][key][d]; scratch after loop
  __shared__ uint16_t Vs[2][2][64 * 64];   // [buf][half][d][key]
  __shared__ uint16_t Ps[8][16 * 64];
  const int bid = blockIdx.x;
  const int bh = (bid & 7) * 4 + (bid >> 7);  // 4 consecutive heads per XCD
  const int jp = (bid >> 3) & 15;
  const int b = bh >> 4, h = bh & 15;
  const int tid = threadIdx.x, w = tid >> 6;
  const int lane = tid & 63, l16 = lane & 15, lg = lane >> 4;
  const bool gA = (w < 4);
  const int wq = w & 3;
  const int q31 = 31 - jp;
  const int NIT = (33 - jp) >> 1;
  const int qbJ = jp * 64 + wq * 16;
  const int qb3 = q31 * 64 + wq * 16;
  const uint16_t* Qg = qkv + (size_t)b * T_ * N3_ + h * DH_;
  const uint16_t* Kg = Qg + H_ * DH_;
  const uint16_t* Vtg = vt + (size_t)bh * DH_ * T_;
  short8 qFj[2], qF3[2];
#pragma unroll
  for (int kf = 0; kf < 2; kf++) {
    qF3[kf] = *(const short8*)(Qg + (size_t)(qb3 + l16) * N3_ + kf * 32 + lg * 8);
    if (gA)
      qFj[kf] = *(const short8*)(Qg + (size_t)(qbJ + l16) * N3_ + kf * 32 + lg * 8);
  }
  const float sk2 = sink[h] * 1.44269504f;
  float mJ = sk2, lJ = (lg == 0) ? 1.f : 0.f;   // A: jp-block state (sink)
  float m3 = gA ? -1e38f : sk2;                 // 31-block: A partial / B (sink)
  float l3 = (!gA && lg == 0) ? 1.f : 0.f;
  f32x4 oJ[4] = {}, o3[4] = {};

  auto STAGE = [&](int buf, int half, int kt) {
    const int row = tid >> 3, c = tid & 7;
    const int cg = c ^ (row & 7);  // pre-swizzled global source (m173)
    gload_lds16(Kg + (size_t)(kt * 64 + row) * N3_ + cg * 8,
                (char*)&Ks[buf][half][0] + w * 1024 + lane * 16);
    gload_lds16(Vtg + (size_t)row * T_ + kt * 64 + cg * 8,
                (char*)&Vs[buf][half][0] + w * 1024 + lane * 16);
  };

  int cur = 0;
  auto computeSub = [&](int sub, int qblkP, int qbR, const short8* qFp,
                        float& mR, float& lR, f32x4* oR) {
    const int half = sub & 1;
    short8 kF[2][4];
#pragma unroll
    for (int kf = 0; kf < 2; kf++)
#pragma unroll
      for (int nf = 0; nf < 4; nf++) {
        const int row = nf * 16 + l16;
        const int cc = (kf * 4 + lg) ^ (l16 & 7);
        kF[kf][nf] = *(const short8*)(&Ks[cur][half][0] + row * 64 + cc * 8);
      }
    f32x4 s[4];
    __builtin_amdgcn_s_setprio(1);
#pragma unroll
    for (int nf = 0; nf < 4; nf++) {
      f32x4 t = {};
      t = __builtin_amdgcn_mfma_f32_16x16x32_bf16(kF[0][nf], qFp[0], t, 0, 0, 0);
      t = __builtin_amdgcn_mfma_f32_16x16x32_bf16(kF[1][nf], qFp[1], t, 0, 0, 0);
      s[nf] = t;
    }
    __builtin_amdgcn_s_setprio(0);
    const bool diag = (sub == qblkP);
    float mt = -3e38f;
    if (diag) {
#pragma unroll
      for (int nf = 0; nf < 4; nf++)
#pragma unroll
        for (int r = 0; r < 4; r++) {
          float v = s[nf][r];
          if (sub * 64 + nf * 16 + lg * 4 + r > qbR + l16) v = -3e38f;
          s[nf][r] = v;
          mt = fmaxf(mt, v);
        }
    } else {
#pragma unroll
      for (int nf = 0; nf < 4; nf++)
#pragma unroll
        for (int r = 0; r < 4; r++) mt = fmaxf(mt, s[nf][r]);
    }
    mt = fmaxf(mt, __shfl_xor(mt, 16));
    mt = fmaxf(mt, __shfl_xor(mt, 32));
    if (!__all(mt <= mR + 8.0f)) {   // T13 defer-rescale
      const float mnew = fmaxf(mR, mt);
      const float alpha = exp2f(mR - mnew);
      mR = mnew;
      lR *= alpha;
      float ar[4];
#pragma unroll
      for (int r = 0; r < 4; r++) ar[r] = __shfl(alpha, lg * 4 + r);
#pragma unroll
      for (int df = 0; df < 4; df++)
#pragma unroll
        for (int r = 0; r < 4; r++) oR[df][r] *= ar[r];
    }
    float ps = 0.f;
#pragma unroll
    for (int nf = 0; nf < 4; nf++)
#pragma unroll
      for (int r = 0; r < 4; r++) {
        const float p = exp2f(s[nf][r] - mR);
        s[nf][r] = p;
        ps += p;
      }
    lR += ps;
#pragma unroll
    for (int nf = 0; nf < 4; nf++) {
      uint2 pw;
      pw.x = cvtpk_bf16(s[nf][0], s[nf][1]);
      pw.y = cvtpk_bf16(s[nf][2], s[nf][3]);
      const int cc = (nf * 2 + (lg >> 1)) ^ (l16 & 7);
      *(uint2*)((char*)&Ps[w][0] + l16 * 128 + cc * 16 + (lg & 1) * 8) = pw;
    }
    __builtin_amdgcn_s_setprio(1);
#pragma unroll
    for (int ks = 0; ks < 2; ks++) {
      const int cp = (ks * 4 + lg) ^ (l16 & 7);
      const short8 pF = *(const short8*)((char*)&Ps[w][0] + l16 * 128 + cp * 16);
#pragma unroll
      for (int df = 0; df < 4; df++) {
        const short8 vF = *(const short8*)((char*)&Vs[cur][half][0] + (df * 16 + l16) * 128 + cp * 16);
        oR[df] = __builtin_amdgcn_mfma_f32_16x16x32_bf16(pF, vF, oR[df], 0, 0, 0);
      }
    }
    __builtin_amdgcn_s_setprio(0);
  };

  STAGE(0, 0, 0);
  STAGE(0, 1, 1);
  __syncthreads();
  for (int kt2 = 0; kt2 < NIT; kt2++) {
    if (kt2 + 1 < NIT) {
      STAGE(cur ^ 1, 0, 2 * kt2 + 2);
      STAGE(cur ^ 1, 1, 2 * kt2 + 3);
    }
    const int s0 = 2 * kt2, s1 = s0 + 1;
    if (gA) {                       // wave-uniform branches
      if (s0 <= jp) computeSub(s0, jp, qbJ, qFj, mJ, lJ, oJ);
      if (s1 <= jp) computeSub(s1, jp, qbJ, qFj, mJ, lJ, oJ);
      if (s0 > jp)  computeSub(s0, q31, qb3, qF3, m3, l3, o3);  // even steal
    } else {
      if (s0 <= jp)  computeSub(s0, q31, qb3, qF3, m3, l3, o3);
      if (s1 <= q31) computeSub(s1, q31, qb3, qF3, m3, l3, o3); // all odds
    }
    __syncthreads();
    cur ^= 1;
  }

  // ---- epilogue: A publishes 31-partial + stores jp rows; B merges + stores ----
  if (gA) {
    l3 += __shfl_xor(l3, 16);
    l3 += __shfl_xor(l3, 32);
    float* sc = (float*)&Ks[0][0][0] + w * 1152;  // 64 lanes x 17 f32 (padded)
#pragma unroll
    for (int df = 0; df < 4; df++)
#pragma unroll
      for (int r = 0; r < 4; r++) sc[lane * 17 + df * 4 + r] = o3[df][r];
    float* ml = (float*)&Ps[w][0];
    if (lg == 0) { ml[l16] = m3; ml[16 + l16] = l3; }
  }
  __syncthreads();
  if (gA) {
    lJ += __shfl_xor(lJ, 16);
    lJ += __shfl_xor(lJ, 32);
#pragma unroll
    for (int r = 0; r < 4; r++) {
      const float inv = 1.f / __shfl(lJ, lg * 4 + r);
      const int qa = qbJ + lg * 4 + r;
      uint16_t* zp = z + (size_t)(b * T_ + qa) * (H_ * DH_) + h * DH_;
#pragma unroll
      for (int df = 0; df < 4; df++) zp[df * 16 + l16] = f2bf(oJ[df][r] * inv);
    }
  } else {
    const float* sc = (const float*)&Ks[0][0][0] + (w - 4) * 1152;
    const float* ml = (const float*)&Ps[w - 4][0];
    const float mA = ml[l16], lA = ml[16 + l16];
    l3 += __shfl_xor(l3, 16);
    l3 += __shfl_xor(l3, 32);
    const float mF = fmaxf(m3, mA);
    const float aB = exp2f(m3 - mF), aA = exp2f(mA - mF);
    const float lF = l3 * aB + lA * aA;
#pragma unroll
    for (int r = 0; r < 4; r++) {
      const float aBr = __shfl(aB, lg * 4 + r);
      const float aAr = __shfl(aA, lg * 4 + r);
      const float inv = 1.f / __shfl(lF, lg * 4 + r);
      const int qa = qb3 + lg * 4 + r;
      uint16_t* zp = z + (size_t)(b * T_ + qa) * (H_ * DH_) + h * DH_;
#pragma unroll
      for (int df = 0; df < 4; df++) {
        const float oA = sc[lane * 17 + df * 4 + r];
        zp[df * 16 + l16] = f2bf((o3[df][r] * aBr + oA * aAr) * inv);
      }
    }
  }
}

extern "C" void kernel_launch(void* const* d_in, const int* in_sizes, int n_in,
                              void* d_out, int out_size, void* d_ws, size_t ws_size,
                              hipStream_t stream) {
  const float* x    = (const float*)d_in[0];
  const float* Wqkv = (const float*)d_in[1];
  const float* bqkv = (const float*)d_in[2];
  const float* Wo   = (const float*)d_in[3];
  const float* bo   = (const float*)d_in[4];
  const float* sink = (const float*)d_in[5];

  // workspace layout (48 MB total):
  //  0- 8 MB : xb (x bf16; dead after gemm1)  /  zb (attn out; aliases xb)
  //  8-14 MB : W_QKV^T bf16
  // 14-16 MB : W_O^T bf16
  // 16-24 MB : Vt[bh][d][t] bf16 (written by gemm1 epilogue)
  // 24-48 MB : qkv bf16 (Q,K used; V region unwritten)
  char* ws = (char*)d_ws;
  uint16_t* xb    = (uint16_t*)(ws);
  uint16_t* zb    = (uint16_t*)(ws);
  uint16_t* wqkvt = (uint16_t*)(ws + (size_t)8  * 1048576);
  uint16_t* wot   = (uint16_t*)(ws + (size_t)14 * 1048576);
  uint16_t* vtb   = (uint16_t*)(ws + (size_t)16 * 1048576);
  uint16_t* qkvb  = (uint16_t*)(ws + (size_t)24 * 1048576);

  k_prep<<<5120, 256, 0, stream>>>(x, Wqkv, Wo, xb, wqkvt, wot);
  k_gemm_bt<true, true, true><<<dim3(M_ / 128, N3_ / 128), 256, 0, stream>>>(
      xb, wqkvt, bqkv, qkvb, vtb, M_, N3_, D_);
  k_attn7<<<dim3(512), 512, 0, stream>>>(qkvb, vtb, sink, zb);
  k_gemm2<<<dim3(M_ / 128, D_ / 64), 256, 0, stream>>>(zb, wot, bo, (float*)d_out);
}